// Round 5
// baseline (300.349 us; speedup 1.0000x reference)
//
#include <hip/hip_runtime.h>
#include <hip/hip_bf16.h>

// Problem constants
#define N_TOK   16384      // B*T
#define HDIM    2048       // H*d_h
#define NH      16
#define DH      128
#define NPAIRS  120
#define KCHUNKS 8
#define NKT     (N_TOK / 64)            // 256 k-tiles of 64 tokens
#define KT_PER_CHUNK (NKT / KCHUNKS)    // 32
#define PANEL_BYTES 8192                // 128 c-rows x 64 tokens x 1B (fp8)

// Workspace layout (bytes) — sum/sumsq/pairC contiguous for a single memset
#define SUM_OFF    0u
#define SUMSQ_OFF  8192u
#define PC_OFF     16384u                     // 120*128*128 f32 = 7,864,320 B
#define XT_OFF     7880704u                   // 2048*16384 fp8 = 33,554,432 B

typedef float     f32x4 __attribute__((ext_vector_type(4)));
typedef long long i64t;
typedef long long i64x2 __attribute__((ext_vector_type(2)));

// ---------------------------------------------------------------- fp8 e4m3 pack
#if __has_builtin(__builtin_amdgcn_cvt_pk_fp8_f32)
__device__ __forceinline__ unsigned pk4_fp8(float a, float b, float c, float d) {
    int w = __builtin_amdgcn_cvt_pk_fp8_f32(a, b, 0, false);   // bytes 0,1
    w = __builtin_amdgcn_cvt_pk_fp8_f32(c, d, w, true);        // bytes 2,3
    return (unsigned)w;
}
#else
__device__ __forceinline__ unsigned char f2e4m3_sw(float f) {
    unsigned u = __float_as_uint(f);
    unsigned s = (u >> 24) & 0x80u;
    unsigned a = u & 0x7fffffffu;
    if (a >= 0x43e00000u) return (unsigned char)(s | 0x7eu);   // clamp to 448
    if (a < 0x3c800000u) {                                     // |x| < 2^-6: subnormal
        float av = __uint_as_float(a);
        int q = (int)rintf(av * 512.0f);                       // units of 2^-9
        return (unsigned char)(s | (unsigned)q);
    }
    unsigned lsb = (a >> 20) & 1u;
    a += 0x7ffffu + lsb;                                       // RNE to 3 mantissa bits
    int e8 = (int)(a >> 23) - 120;
    unsigned m = (a >> 20) & 7u;
    return (unsigned char)(s | ((unsigned)e8 << 3) | m);
}
__device__ __forceinline__ unsigned pk4_fp8(float a, float b, float c, float d) {
    return (unsigned)f2e4m3_sw(a) | ((unsigned)f2e4m3_sw(b) << 8) |
           ((unsigned)f2e4m3_sw(c) << 16) | ((unsigned)f2e4m3_sw(d) << 24);
}
#endif

// ---------------------------------------------------------------- pass 1: fused stats + panelized transpose + fp8
// Panel layout (K-interleaved for b128 fragment reads):
//   row d, chunk c (16 B) = tokens [8c..8c+7 | 32+8c..32+8c+7]
__global__ __launch_bounds__(256)
void stats_transpose_kernel(const float* __restrict__ X,
                            float* __restrict__ sum, float* __restrict__ sumsq,
                            unsigned char* __restrict__ Xt) {
    __shared__ float tile[64][129];               // stride 129
    __shared__ float sred[4][32][8];              // cross-wave stats partials
    const int h  = blockIdx.x;                    // 0..15
    const int by = blockIdx.y;                    // 0..255
    const int n0 = by * 64;
    const int tx = threadIdx.x;
    const int w  = tx >> 6, l = tx & 63;
    const int cq = tx & 31;                       // float4 index within 128-col slice
    const int rq0 = tx >> 5;                      // 0..7

    float4 s  = make_float4(0.f, 0.f, 0.f, 0.f);
    float4 ss = make_float4(0.f, 0.f, 0.f, 0.f);
    #pragma unroll
    for (int it = 0; it < 8; ++it) {
        int r = it * 8 + rq0;
        float4 x = *(const float4*)(X + (size_t)(n0 + r) * HDIM + h * DH + cq * 4);
        s.x += x.x; s.y += x.y; s.z += x.z; s.w += x.w;
        ss.x += x.x * x.x; ss.y += x.y * x.y; ss.z += x.z * x.z; ss.w += x.w * x.w;
        tile[r][cq * 4 + 0] = x.x; tile[r][cq * 4 + 1] = x.y;
        tile[r][cq * 4 + 2] = x.z; tile[r][cq * 4 + 3] = x.w;
    }
    s.x += __shfl_down(s.x, 32);  s.y += __shfl_down(s.y, 32);
    s.z += __shfl_down(s.z, 32);  s.w += __shfl_down(s.w, 32);
    ss.x += __shfl_down(ss.x, 32); ss.y += __shfl_down(ss.y, 32);
    ss.z += __shfl_down(ss.z, 32); ss.w += __shfl_down(ss.w, 32);
    if (l < 32) {
        sred[w][l][0] = s.x;  sred[w][l][1] = s.y;
        sred[w][l][2] = s.z;  sred[w][l][3] = s.w;
        sred[w][l][4] = ss.x; sred[w][l][5] = ss.y;
        sred[w][l][6] = ss.z; sred[w][l][7] = ss.w;
    }
    __syncthreads();
    if (tx < 32) {                                // wave 0 finishes stats
        float a0 = 0.f, a1 = 0.f, a2 = 0.f, a3 = 0.f;
        float b0 = 0.f, b1 = 0.f, b2 = 0.f, b3 = 0.f;
        #pragma unroll
        for (int w2 = 0; w2 < 4; ++w2) {
            a0 += sred[w2][tx][0]; a1 += sred[w2][tx][1];
            a2 += sred[w2][tx][2]; a3 += sred[w2][tx][3];
            b0 += sred[w2][tx][4]; b1 += sred[w2][tx][5];
            b2 += sred[w2][tx][6]; b3 += sred[w2][tx][7];
        }
        int c = h * DH + tx * 4;
        atomicAdd(&sum[c + 0], a0);  atomicAdd(&sum[c + 1], a1);
        atomicAdd(&sum[c + 2], a2);  atomicAdd(&sum[c + 3], a3);
        atomicAdd(&sumsq[c + 0], b0); atomicAdd(&sumsq[c + 1], b1);
        atomicAdd(&sumsq[c + 2], b2); atomicAdd(&sumsq[c + 3], b3);
    }
    // transpose write: 512 16B-chunks, K-interleaved token order
    unsigned char* panel = Xt + ((size_t)h * NKT + by) * PANEL_BYTES;
    #pragma unroll
    for (int it = 0; it < 2; ++it) {
        int q = it * 256 + tx;
        int d = q >> 2, c = q & 3;
        int t0 = c * 8;
        uint4 pk;
        pk.x = pk4_fp8(tile[t0+ 0][d], tile[t0+ 1][d], tile[t0+ 2][d], tile[t0+ 3][d]);
        pk.y = pk4_fp8(tile[t0+ 4][d], tile[t0+ 5][d], tile[t0+ 6][d], tile[t0+ 7][d]);
        pk.z = pk4_fp8(tile[32+t0+0][d], tile[32+t0+1][d], tile[32+t0+2][d], tile[32+t0+3][d]);
        pk.w = pk4_fp8(tile[32+t0+4][d], tile[32+t0+5][d], tile[32+t0+6][d], tile[32+t0+7][d]);
        *(uint4*)(panel + d * 64 + c * 16) = pk;
    }
}

// ---------------------------------------------------------------- pass 2: pairwise raw Gram via fp8 MFMA
__device__ __forceinline__ void gload16(const void* gsrc, void* ldst) {
    __builtin_amdgcn_global_load_lds(
        (const __attribute__((address_space(1))) unsigned int*)gsrc,
        (__attribute__((address_space(3))) unsigned int*)ldst,
        16, 0, 0);
}

__global__ __launch_bounds__(256, 4)
void gram_kernel(const unsigned char* __restrict__ Xt, float* __restrict__ pairC) {
    const int kc = blockIdx.x;                    // K-chunk 0..7 -> XCD kc (linear%8)
    const int p  = blockIdx.y;                    // pair 0..119
    int i = 0, rem = p;
    while (rem >= NH - 1 - i) { rem -= NH - 1 - i; ++i; }
    const int j = i + 1 + rem;

    __shared__ alignas(16) unsigned char ldsA[2][PANEL_BYTES];   // 16 KB (dbuf)
    __shared__ alignas(16) unsigned char ldsB[2][PANEL_BYTES];   // 16 KB

    const int tx = threadIdx.x;
    const int w  = tx >> 6, l = tx & 63;
    const int wm = w >> 1, wn = w & 1;            // 2x2 wave grid over 128x128
    const int l15 = l & 15, quad = l >> 4;

    // Staging: physical chunk p = r*4 + cp holds source chunk c = cp ^ ((r>>1)&3)
    unsigned int goff[2];
    int ldsOff[2];
    #pragma unroll
    for (int s = 0; s < 2; ++s) {
        int pi = s * 256 + tx;
        int r = pi >> 2, cp = pi & 3;
        int c = cp ^ ((r >> 1) & 3);
        goff[s]   = (unsigned int)(r * 64 + c * 16);
        ldsOff[s] = s * 4096 + w * 1024;          // wave-uniform LDS base per issue
    }
    const char* Abase = (const char*)Xt + ((size_t)i * NKT + (size_t)kc * KT_PER_CHUNK) * PANEL_BYTES;
    const char* Bbase = (const char*)Xt + ((size_t)j * NKT + (size_t)kc * KT_PER_CHUNK) * PANEL_BYTES;

    f32x4 acc[4][4];
    #pragma unroll
    for (int mi = 0; mi < 4; ++mi)
        #pragma unroll
        for (int ni = 0; ni < 4; ++ni)
            acc[mi][ni] = (f32x4){0.f, 0.f, 0.f, 0.f};

    const int rsw = (l15 >> 1) & 3;               // fragment-read chunk swizzle
    const int cp  = quad ^ rsw;                   // physical chunk (mi-independent)

    // prologue: stage kt=0 into buf 0
    {
        const char* pa = Abase;
        const char* pb = Bbase;
        gload16(pa + goff[0], (char*)ldsA[0] + ldsOff[0]);
        gload16(pa + goff[1], (char*)ldsA[0] + ldsOff[1]);
        gload16(pb + goff[0], (char*)ldsB[0] + ldsOff[0]);
        gload16(pb + goff[1], (char*)ldsB[0] + ldsOff[1]);
    }

    for (int kt = 0; kt < KT_PER_CHUNK; ++kt) {
        const int cur = kt & 1;
        __syncthreads();                          // drains prev-iter loads (had full compute to land)
        if (kt + 1 < KT_PER_CHUNK) {
            const char* pa = Abase + (size_t)(kt + 1) * PANEL_BYTES;
            const char* pb = Bbase + (size_t)(kt + 1) * PANEL_BYTES;
            gload16(pa + goff[0], (char*)ldsA[1 - cur] + ldsOff[0]);
            gload16(pa + goff[1], (char*)ldsA[1 - cur] + ldsOff[1]);
            gload16(pb + goff[0], (char*)ldsB[1 - cur] + ldsOff[0]);
            gload16(pb + goff[1], (char*)ldsB[1 - cur] + ldsOff[1]);
        }
        // fragment reads: one b128 per (mi/ni) covers BOTH kh steps
        i64x2 a[4], b[4];
        #pragma unroll
        for (int mi = 0; mi < 4; ++mi) {
            int r = wm * 64 + mi * 16 + l15;
            a[mi] = *(const i64x2*)(ldsA[cur] + r * 64 + cp * 16);
        }
        #pragma unroll
        for (int ni = 0; ni < 4; ++ni) {
            int r = wn * 64 + ni * 16 + l15;
            b[ni] = *(const i64x2*)(ldsB[cur] + r * 64 + cp * 16);
        }
        #pragma unroll
        for (int kh = 0; kh < 2; ++kh)
            #pragma unroll
            for (int mi = 0; mi < 4; ++mi)
                #pragma unroll
                for (int ni = 0; ni < 4; ++ni)
                    acc[mi][ni] = __builtin_amdgcn_mfma_f32_16x16x32_fp8_fp8(
                        a[mi][kh], b[ni][kh], acc[mi][ni], 0, 0, 0);
    }

    // Epilogue: partial raw Gram -> atomic accumulate (KCHUNKS contenders/address)
    float* pc = pairC + (size_t)p * (DH * DH);
    #pragma unroll
    for (int mi = 0; mi < 4; ++mi)
        #pragma unroll
        for (int ni = 0; ni < 4; ++ni)
            #pragma unroll
            for (int r = 0; r < 4; ++r) {
                int row = wm * 64 + mi * 16 + quad * 4 + r;  // d (head-i dim)
                int col = wn * 64 + ni * 16 + l15;           // e (head-j dim)
                atomicAdd(&pc[row * DH + col], acc[mi][ni][r]);
            }
}

// ---------------------------------------------------------------- pass 3: per-pair loss (inline mu/rinv) + final
__global__ void pair_reduce_kernel(const float* __restrict__ pairC, const float* __restrict__ G,
                                   const float* __restrict__ sum, const float* __restrict__ sumsq,
                                   float* __restrict__ out) {
    int p = blockIdx.x;
    int i = 0, rem = p;
    while (rem >= NH - 1 - i) { rem -= NH - 1 - i; ++i; }
    int j = i + 1 + rem;
    __shared__ float smui[DH], smuj[DH], sri[DH], srj[DH];
    {
        int t = threadIdx.x & 127;
        int h = (threadIdx.x < 128) ? i : j;
        int c = h * DH + t;
        float m = sum[c] * (1.f / (float)N_TOK);
        float var = (sumsq[c] - (float)N_TOK * m * m) * (1.f / (float)(N_TOK - 1));
        var = fmaxf(var, 0.f);
        float rv = 1.f / (sqrtf(var) + 1e-8f);
        if (threadIdx.x < 128) { smui[t] = m; sri[t] = rv; }
        else                   { smuj[t] = m; srj[t] = rv; }
    }
    __syncthreads();
    const float invN = 1.f / (float)N_TOK;
    const float* pc = pairC + (size_t)p * (DH * DH);
    float s = 0.f;
    for (int idx = threadIdx.x; idx < DH * DH; idx += 256) {
        int d = idx >> 7, e = idx & 127;
        float cn = (pc[idx] * invN - smui[d] * smuj[e]) * sri[d] * srj[e];
        float diff = cn - ((d == e) ? 1.f : 0.f);
        s += diff * diff;
    }
    for (int o = 32; o; o >>= 1) s += __shfl_down(s, o);
    __shared__ float red[4];
    if ((threadIdx.x & 63) == 0) red[threadIdx.x >> 6] = s;
    __syncthreads();
    if (threadIdx.x == 0) {
        float t = red[0] + red[1] + red[2] + red[3];
        float x = -15.99f * (G[i * NH + j] - 0.0f);
        float sp = (x > 20.f) ? x : log1pf(expf(x));
        float wgt = 0.929f + (1.f - 0.929f) * sp;
        atomicAdd(out, wgt * t * (1.f / (float)NPAIRS));
    }
}

// ---------------------------------------------------------------- launcher
extern "C" void kernel_launch(void* const* d_in, const int* in_sizes, int n_in,
                              void* d_out, int out_size, void* d_ws, size_t ws_size,
                              hipStream_t stream) {
    const float* X = (const float*)d_in[0];
    const float* G = (const float*)d_in[1];
    float* out = (float*)d_out;
    char* ws = (char*)d_ws;

    float*         sum   = (float*)(ws + SUM_OFF);
    float*         sumsq = (float*)(ws + SUMSQ_OFF);
    float*         pairC = (float*)(ws + PC_OFF);
    unsigned char* Xt    = (unsigned char*)(ws + XT_OFF);

    // one memset covers sum + sumsq + pairC (contiguous)
    hipMemsetAsync(ws, 0, PC_OFF + (size_t)NPAIRS * DH * DH * 4, stream);
    hipMemsetAsync(d_out, 0, 4, stream);

    stats_transpose_kernel<<<dim3(16, 256), 256, 0, stream>>>(X, sum, sumsq, Xt);
    gram_kernel<<<dim3(KCHUNKS, NPAIRS), 256, 0, stream>>>(Xt, pairC);
    pair_reduce_kernel<<<NPAIRS, 256, 0, stream>>>(pairC, G, sum, sumsq, out);
}